// Round 3
// baseline (253.232 us; speedup 1.0000x reference)
//
#include <hip/hip_runtime.h>
#include <hip/hip_bf16.h>

#define DIM    1024
#define HEADS  16
#define DH     64
#define SEG    512
#define PMEMN  16
#define TOK    8192        // 2*4096 tokens = 16 segments * 512
#define NQKV   3072
#define JPAD   544         // PMEM + SEG + 16 zero-pad (17 tiles of 32)
#define NSH    256         // 16 segments * 16 heads
#define VTS    129         // (128-col kernels) v-transpose LDS stride
#define QK2    264         // 256-col bf16 stage stride (528B, 16B-aligned)
#define VF2    260         // 256-col fp32 stage stride (1040B, 16B-aligned)
#define VT2    257         // 256-col bf16 transpose stride (odd)

typedef __hip_bfloat16 bf16;
typedef __attribute__((ext_vector_type(8))) short short8;   // 8 bf16 = 4 VGPRs
typedef __attribute__((ext_vector_type(4))) float floatx4;  // MFMA C/D frag

__device__ __forceinline__ short8 ld_frag(const bf16* p) {
    return *(const short8*)p;
}
__device__ __forceinline__ floatx4 mfma16(short8 a, short8 b, floatx4 c) {
    return __builtin_amdgcn_mfma_f32_16x16x32_bf16(a, b, c, 0, 0, 0);
}
__device__ __forceinline__ void st_out(bf16* p, float v) { *p = __float2bfloat16(v); }
__device__ __forceinline__ void st_out(float* p, float v) { *p = v; }
// async global->LDS DMA, 16 B per lane; LDS dest must be wave base + lane*16
__device__ __forceinline__ void g2lds16(const bf16* g, bf16* l) {
    __builtin_amdgcn_global_load_lds((const __attribute__((address_space(1))) void*)g,
                                     (__attribute__((address_space(3))) void*)l, 16, 0, 0);
}

// ---------------- RMSNorm: fp32 in -> bf16 normalized ----------------
__global__ void rmsnorm_kernel(const float* __restrict__ x, const float* __restrict__ wgt,
                               bf16* __restrict__ xn) {
    int row = blockIdx.x;
    int tid = threadIdx.x;              // 256 threads, 4 floats each
    const float4* xr = (const float4*)(x + (long)row * DIM);
    float4 v = xr[tid];
    float ss = v.x * v.x + v.y * v.y + v.z * v.z + v.w * v.w;
    #pragma unroll
    for (int off = 32; off; off >>= 1) ss += __shfl_xor(ss, off);
    __shared__ float red[4];
    if ((tid & 63) == 0) red[tid >> 6] = ss;
    __syncthreads();
    float tot = red[0] + red[1] + red[2] + red[3];
    float sc = rsqrtf(tot * (1.0f / DIM) + 1.1920929e-07f);
    const float4* wr = (const float4*)wgt;
    float4 w4 = wr[tid];
    bf16* o = xn + (long)row * DIM + tid * 4;
    o[0] = __float2bfloat16(v.x * sc * w4.x);
    o[1] = __float2bfloat16(v.y * sc * w4.y);
    o[2] = __float2bfloat16(v.z * sc * w4.z);
    o[3] = __float2bfloat16(v.w * sc * w4.w);
}

// ---- merged transpose + cast: wqkv [1024][3072] and wout [1024][1024] -> bf16 [C][R] ----
__global__ void transpose_w2(const float* __restrict__ wqkv, const float* __restrict__ wout,
                             bf16* __restrict__ wqkvT, bf16* __restrict__ woutT) {
    __shared__ float tile[32][33];
    int bx = blockIdx.x;
    const float* in; bf16* out; int C, c0;
    if (bx < 96) { in = wqkv; out = wqkvT; C = NQKV; c0 = bx * 32; }
    else         { in = wout; out = woutT; C = DIM;  c0 = (bx - 96) * 32; }
    const int R = DIM;
    int r0 = blockIdx.y * 32;
    int tx = threadIdx.x, ty = threadIdx.y;      // (32,8)
    #pragma unroll
    for (int i = 0; i < 4; i++)
        tile[ty + i * 8][tx] = in[(long)(r0 + ty + i * 8) * C + c0 + tx];
    __syncthreads();
    #pragma unroll
    for (int i = 0; i < 4; i++)
        out[(long)(c0 + ty + i * 8) * R + r0 + tx] = __float2bfloat16(tile[tx][ty + i * 8]);
}

// ------- out-projection GEMM: C[M][N] = A[M][K]*Bt[N][K]^T, fp32 out via LDS stage -------
__global__ __launch_bounds__(256)
void gemm_bt_f(const bf16* __restrict__ A, const bf16* __restrict__ Bt,
               float* __restrict__ C, int M, int N, int K) {
    __shared__ __align__(16) bf16 SMu[128 * 136];    // 34816 B; K-loop uses first 32 KB
    bf16* As = SMu;
    bf16* Bs = SMu + 128 * 64;
    const int tid = threadIdx.x;
    const int wv = tid >> 6;
    const int lane = tid & 63;
    const int quad = lane >> 4, l15 = lane & 15;
    const int wm = (wv >> 1) * 64, wn = (wv & 1) * 64;
    const int bm = blockIdx.x, bn = blockIdx.y;

    const int srow = tid >> 3;
    const int sgch = (tid & 7) ^ (srow & 7);
    const bf16* Ag = A + (long)(bm * 128 + srow) * K + sgch * 8;
    const bf16* Bg = Bt + (long)(bn * 128 + srow) * K + sgch * 8;
    const long row32 = (long)32 * K;

    const int rx0 = ((0 + quad) ^ (l15 & 7)) * 8;
    const int rx1 = ((4 + quad) ^ (l15 & 7)) * 8;

    floatx4 acc[4][4] = {};

    for (int k0 = 0; k0 < K; k0 += 64) {
        __syncthreads();
        #pragma unroll
        for (int i = 0; i < 4; i++) {
            g2lds16(Ag + i * row32 + k0, As + i * 2048 + tid * 8);
            g2lds16(Bg + i * row32 + k0, Bs + i * 2048 + tid * 8);
        }
        __syncthreads();
        #pragma unroll
        for (int kk = 0; kk < 2; kk++) {
            const int rx = kk ? rx1 : rx0;
            short8 af[4], bfr[4];
            #pragma unroll
            for (int i = 0; i < 4; i++) af[i] = ld_frag(&As[(wm + i * 16 + l15) * 64 + rx]);
            #pragma unroll
            for (int j = 0; j < 4; j++) bfr[j] = ld_frag(&Bs[(wn + j * 16 + l15) * 64 + rx]);
            #pragma unroll
            for (int i = 0; i < 4; i++)
                #pragma unroll
                for (int j = 0; j < 4; j++)
                    acc[i][j] = mfma16(af[i], bfr[j], acc[i][j]);
        }
    }
    // ---- fp32 C-write via LDS half-staging: full-line float4 stores ----
    float* SMf = (float*)SMu;            // 64 x 132 fp32
    #pragma unroll
    for (int half = 0; half < 2; half++) {
        __syncthreads();                 // half0: also guards As/Bs reuse
        if ((wv >> 1) == half) {
            #pragma unroll
            for (int i = 0; i < 4; i++)
                #pragma unroll
                for (int j = 0; j < 4; j++)
                    #pragma unroll
                    for (int r = 0; r < 4; r++)
                        SMf[(i * 16 + quad * 4 + r) * 132 + wn + j * 16 + l15] = acc[i][j][r];
        }
        __syncthreads();
        #pragma unroll
        for (int it = 0; it < 8; it++) {
            int cid = it * 256 + tid;
            int rr = cid >> 5, cc = cid & 31;          // 64 rows x 32 float4-chunks
            float4 v4 = *(const float4*)&SMf[rr * 132 + cc * 4];
            *(float4*)&C[(long)(bm * 128 + half * 64 + rr) * N + bn * 128 + cc * 4] = v4;
        }
    }
}

// ======= QKV GEMM, 256x256 tile, 8 waves, 4-phase/K-tile counted-vmcnt schedule =======
// Phase (mh,nh) computes C-quadrant [mh*128,+128) x [nh*128,+128); all 8 waves
// work the same quadrant (wave piece 32x64), so phase p needs only A-half(mh),
// B-half(nh). Half-tiles of K-tile t+1 are issued one per phase of tile t in
// order A0,B0,B1,A1; with in-order vmem completion, vmcnt(4) at the ends of
// P1/P2/P4 guarantees each phase's halves landed 2-3 phases after issue.
__global__ __launch_bounds__(512, 2)
void gemm_qkv_ep(const bf16* __restrict__ A, const bf16* __restrict__ Bt,
                 bf16* __restrict__ qbuf, bf16* __restrict__ kpad,
                 bf16* __restrict__ vtpad, float* __restrict__ origv) {
    __shared__ __align__(16) bf16 SMEM[65536];   // 128 KiB: As[2][16384] | Bs[2][16384]
    const int tid = threadIdx.x;
    const int wv = tid >> 6;                      // 0..7
    const int lane = tid & 63;
    const int quad = lane >> 4, l15 = lane & 15;
    const int qrow = wv >> 1;                     // 0..3 (32-row band in quadrant)
    const int qcol = wv & 1;                      // 0..1 (64-col band in quadrant)
    const int bm = blockIdx.x, bn = blockIdx.y;

    const int rowt = tid >> 3;                    // 0..63
    const int sgch = (tid & 7) ^ (rowt & 7);      // source chunk pre-swizzle
    const bf16* Asrc = A  + (long)(bm * 256 + rowt) * DIM + sgch * 8;
    const bf16* Bsrc = Bt + (long)(bn * 256 + rowt) * DIM + sgch * 8;

    // stage half h of a 256x64 K-tile: 2 G-loads x 512 threads x 16B = 16 KB
#define STG_A(buf, h, kt) do { \
        g2lds16(Asrc + (long)((h) * 128 +  0) * DIM + (kt) * 64, SMEM + (buf) * 16384 + ((h) * 128 +  0) * 64 + tid * 8); \
        g2lds16(Asrc + (long)((h) * 128 + 64) * DIM + (kt) * 64, SMEM + (buf) * 16384 + ((h) * 128 + 64) * 64 + tid * 8); \
    } while (0)
#define STG_B(buf, h, kt) do { \
        g2lds16(Bsrc + (long)((h) * 128 +  0) * DIM + (kt) * 64, SMEM + 32768 + (buf) * 16384 + ((h) * 128 +  0) * 64 + tid * 8); \
        g2lds16(Bsrc + (long)((h) * 128 + 64) * DIM + (kt) * 64, SMEM + 32768 + (buf) * 16384 + ((h) * 128 + 64) * 64 + tid * 8); \
    } while (0)

    floatx4 acc[2][2][2][4] = {};   // [mh][nh][m][n]

#define PHASE(CUR, MH, NH, STGBLK, DOWAIT) do { \
        short8 af[2][2], bfv[2][4]; \
        _Pragma("unroll") \
        for (int m = 0; m < 2; m++) \
            _Pragma("unroll") \
            for (int kk = 0; kk < 2; kk++) \
                af[kk][m] = ld_frag(&SMEM[(CUR) * 16384 + ((MH) * 128 + qrow * 32 + m * 16 + l15) * 64 + ((kk * 4 + quad) ^ (l15 & 7)) * 8]); \
        _Pragma("unroll") \
        for (int n = 0; n < 4; n++) \
            _Pragma("unroll") \
            for (int kk = 0; kk < 2; kk++) \
                bfv[kk][n] = ld_frag(&SMEM[32768 + (CUR) * 16384 + ((NH) * 128 + qcol * 64 + n * 16 + l15) * 64 + ((kk * 4 + quad) ^ (l15 & 7)) * 8]); \
        STGBLK; \
        __builtin_amdgcn_s_barrier(); \
        asm volatile("s_waitcnt lgkmcnt(0)" ::: "memory"); \
        __builtin_amdgcn_sched_barrier(0); \
        __builtin_amdgcn_s_setprio(1); \
        _Pragma("unroll") \
        for (int m = 0; m < 2; m++) \
            _Pragma("unroll") \
            for (int n = 0; n < 4; n++) { \
                acc[MH][NH][m][n] = mfma16(af[0][m], bfv[0][n], acc[MH][NH][m][n]); \
                acc[MH][NH][m][n] = mfma16(af[1][m], bfv[1][n], acc[MH][NH][m][n]); \
            } \
        __builtin_amdgcn_s_setprio(0); \
        if (DOWAIT) { asm volatile("s_waitcnt vmcnt(4)" ::: "memory"); } \
        __builtin_amdgcn_s_barrier(); \
    } while (0)

    // prologue: K-tile 0 into buf0, order A0,B0,B1,A1
    STG_A(0, 0, 0); STG_B(0, 0, 0); STG_B(0, 1, 0); STG_A(0, 1, 0);
    asm volatile("s_waitcnt vmcnt(4)" ::: "memory");
    __builtin_amdgcn_s_barrier();

    for (int kt2 = 0; kt2 < 16; kt2 += 2) {
        {   // tile kt2 from buf0, stage kt2+1 into buf1
            const int kn = kt2 + 1;
            PHASE(0, 0, 0, STG_A(1, 0, kn), 1);
            PHASE(0, 0, 1, STG_B(1, 0, kn), 1);
            PHASE(0, 1, 0, STG_B(1, 1, kn), 0);
            PHASE(0, 1, 1, STG_A(1, 1, kn), 1);
        }
        {   // tile kt2+1 from buf1, stage kt2+2 into buf0 (dummy re-stage for last)
            const int kn = (kt2 + 2 < 16) ? kt2 + 2 : 15;
            PHASE(1, 0, 0, STG_A(0, 0, kn), 1);
            PHASE(1, 0, 1, STG_B(0, 0, kn), 1);
            PHASE(1, 1, 0, STG_B(0, 1, kn), 0);
            PHASE(1, 1, 1, STG_A(0, 1, kn), 1);
        }
    }
    asm volatile("s_waitcnt vmcnt(0)" ::: "memory");   // drain dummies before LDS reuse
    __builtin_amdgcn_s_barrier();
#undef PHASE
#undef STG_A
#undef STG_B

    const int tok0 = bm * 256;
    const int seg = tok0 >> 9;          // block fully inside one segment (256 | 512)
    const int s0 = tok0 & 511;

    if (bn < 8) {
        // ---- q (bn<4) or k block: rope in-register, stage bf16, vector stores ----
        const bool isq = (bn < 4);
        const int cb = (bn & 3) * 256;                 // dcol base within q or k
        #pragma unroll
        for (int mh = 0; mh < 2; mh++) {
            __syncthreads();
            #pragma unroll
            for (int nh = 0; nh < 2; nh++)
                #pragma unroll
                for (int n = 0; n < 4; n++) {
                    int col = nh * 128 + qcol * 64 + n * 16 + l15;
                    int dcol = cb + col;
                    int dh = dcol & 63;
                    int pr = dh >> 1;
                    float invf = __expf(-(float)pr * (9.210340371976184f / 32.0f));
                    const bool odd = dh & 1;
                    #pragma unroll
                    for (int m = 0; m < 2; m++)
                        #pragma unroll
                        for (int r = 0; r < 4; r++) {
                            int lrow = qrow * 32 + m * 16 + quad * 4 + r;   // 0..127
                            int sl = s0 + mh * 128 + lrow;
                            float sn, cs;
                            __sincosf((float)sl * invf, &sn, &cs);
                            float v = acc[mh][nh][m][n][r];
                            float px = __shfl_xor(v, 1);
                            float y = odd ? (v * cs + px * sn) : (v * cs - px * sn);
                            if (isq) y *= 0.125f;      // fold DH^-0.5 (exact)
                            SMEM[lrow * QK2 + col] = __float2bfloat16(y);
                        }
                }
            __syncthreads();
            #pragma unroll
            for (int it = 0; it < 8; it++) {
                int cid = it * 512 + tid;
                int rr = cid >> 5, cc = cid & 31;      // 128 rows x 32 short8-chunks
                short8 pk = *(const short8*)&SMEM[rr * QK2 + cc * 8];
                if (isq) {
                    *(short8*)&qbuf[(long)(tok0 + mh * 128 + rr) * DIM + cb + cc * 8] = pk;
                } else {
                    int dcol = cb + cc * 8;
                    int h = dcol >> 6, dh = dcol & 63;
                    *(short8*)&kpad[(((long)(seg * 16 + h) * JPAD) + PMEMN + s0 + mh * 128 + rr) * DH + dh] = pk;
                }
            }
        }
    } else {
        // ---- v block: origv fp32 quarter-staging + bf16 transpose halves -> vtpad ----
        const int vb = (bn - 8) * 256;
        float* SMf = (float*)SMEM;                     // 64 x VF2 fp32
        #pragma unroll
        for (int qt = 0; qt < 4; qt++) {
            __syncthreads();
            if ((qrow >> 1) == (qt & 1)) {             // waves owning rows qt*64..+63
                #pragma unroll
                for (int nh = 0; nh < 2; nh++)
                    #pragma unroll
                    for (int m = 0; m < 2; m++)
                        #pragma unroll
                        for (int n = 0; n < 4; n++)
                            #pragma unroll
                            for (int r = 0; r < 4; r++)
                                SMf[((qrow & 1) * 32 + m * 16 + quad * 4 + r) * VF2 + nh * 128 + qcol * 64 + n * 16 + l15] =
                                    acc[qt >> 1][nh][m][n][r];
            }
            __syncthreads();
            #pragma unroll
            for (int it = 0; it < 8; it++) {
                int cid = it * 512 + tid;
                int rr = cid >> 6, cc = cid & 63;      // 64 rows x 64 float4-chunks
                float4 v4 = *(const float4*)&SMf[rr * VF2 + cc * 4];
                int sl = s0 + qt * 64 + rr;
                int vcol = vb + cc * 4;
                int h = vcol >> 6, dh = vcol & 63;
                *(float4*)&origv[((long)(seg * 16 + h) * SEG + sl) * DH + dh] = v4;
            }
        }
        #pragma unroll
        for (int hf = 0; hf < 2; hf++) {
            __syncthreads();
            #pragma unroll
            for (int nh = 0; nh < 2; nh++)
                #pragma unroll
                for (int m = 0; m < 2; m++)
                    #pragma unroll
                    for (int n = 0; n < 4; n++)
                        #pragma unroll
                        for (int r = 0; r < 4; r++)
                            SMEM[(qrow * 32 + m * 16 + quad * 4 + r) * VT2 + nh * 128 + qcol * 64 + n * 16 + l15] =
                                __float2bfloat16(acc[hf][nh][m][n][r]);
            __syncthreads();
            #pragma unroll
            for (int it = 0; it < 8; it++) {
                int cid = it * 512 + tid;
                int orow = cid >> 4;                   // local v-col 0..255
                int tch = cid & 15;                    // token chunk of 8
                int vcol = vb + orow;
                int h = vcol >> 6, dh = vcol & 63;
                short8 pk;
                #pragma unroll
                for (int k = 0; k < 8; k++)
                    pk[k] = __builtin_bit_cast(short, SMEM[(tch * 8 + k) * VT2 + orow]);
                *(short8*)&vtpad[(((long)(seg * 16 + h) * DH + dh) * JPAD) + PMEMN + s0 + hf * 128 + tch * 8] = pk;
            }
        }
    }
}

// ------------- pmem rows into kpad/vtpad + zero tail pad -------------
__global__ void fill_pmem_pad(const float* __restrict__ pmem, bf16* __restrict__ kpad,
                              bf16* __restrict__ vtpad) {
    int gid = blockIdx.x * 256 + threadIdx.x;
    int dh = gid & 63, j = (gid >> 6) & 15, sh = gid >> 10;
    int h = sh & 15;
    float kv = pmem[((0 * HEADS + h) * PMEMN + j) * DH + dh];
    float vv = pmem[((1 * HEADS + h) * PMEMN + j) * DH + dh];
    kpad[((long)sh * JPAD + j) * DH + dh] = __float2bfloat16(kv);
    vtpad[((long)sh * DH + dh) * JPAD + j] = __float2bfloat16(vv);
    kpad[((long)sh * JPAD + PMEMN + SEG + j) * DH + dh] = __float2bfloat16(0.0f);
    vtpad[((long)sh * DH + dh) * JPAD + PMEMN + SEG + j] = __float2bfloat16(0.0f);
}

// ------- flash attention v3: 1 wave = 32 q rows, NO block barriers in K-loop -------
__global__ __launch_bounds__(256, 3)
void flash_attn(const bf16* __restrict__ qbuf, const bf16* __restrict__ kpad,
                const bf16* __restrict__ vtpad, bf16* __restrict__ attn_out) {
    const int bid = blockIdx.x;
    const int sh = bid & (NSH - 1);
    const int qblk = bid >> 8;
    const int wv = threadIdx.x >> 6;
    const int lane = threadIdx.x & 63;
    const int quad = lane >> 4, l15 = lane & 15;
    const int qr0 = qblk * 128 + wv * 32;
    const int bw = sh >> 4, h = sh & 15;

    __shared__ __align__(16) short pbuf[4][32 * 32];   // per-wave P tile
    short* pb = pbuf[wv];

    const bf16* qr_g0 = qbuf + (long)(bw * SEG + qr0 + l15) * DIM + h * DH;
    const bf16* qr_g1 = qbuf + (long)(bw * SEG + qr0 + 16 + l15) * DIM + h * DH;
    short8 aq[2][2] = {{ld_frag(qr_g0 + quad * 8), ld_frag(qr_g0 + 32 + quad * 8)},
                       {ld_frag(qr_g1 + quad * 8), ld_frag(qr_g1 + 32 + quad * 8)}};

    // ones B-fragment: B[k][0]=1 -> D[:,0] = row-sum of P
    const short bf16one = (short)0x3F80;
    short8 onesB;
    #pragma unroll
    for (int i = 0; i < 8; i++) onesB[i] = (l15 == 0) ? bf16one : (short)0;

    float mrow[2][4];
    floatx4 o[2][4] = {};
    floatx4 lac[2] = {};
    #pragma unroll
    for (int g = 0; g < 2; g++)
        #pragma unroll
        for (int r = 0; r < 4; r++) mrow[g][r] = -1e30f;

    const bf16* kb = kpad + (long)sh * JPAD * DH;
    const bf16* vbp = vtpad + (long)sh * DH * JPAD;

    const int ntiles = (qr0 + 47) / 32 + 1;

    short8 kf[4];
    {
        const bf16* kr0 = kb + (long)l15 * DH;
        const bf16* kr1 = kb + (long)(16 + l15) * DH;
        kf[0] = ld_frag(kr0 + quad * 8);  kf[1] = ld_frag(kr0 + 32 + quad * 8);
        kf[2] = ld_frag(kr1 + quad * 8);  kf[3] = ld_frag(kr1 + 32 + quad * 8);
    }

    for (int jt = 0; jt < ntiles; ++jt) {
        const int j0 = jt * 32;
        short8 bv[4];
        #pragma unroll
        for (int n = 0; n < 4; n++)
            bv[n] = ld_frag(vbp + (long)(n * 16 + l15) * JPAD + j0 + quad * 8);

        floatx4 sc[2][2];
        #pragma unroll
        for (int g = 0; g < 2; g++) {
            sc[g][0] = mfma16(aq[g][1], kf[1], mfma16(aq[g][0], kf[0], floatx4{}));
            sc[g][1] = mfma16(aq[g][1], kf[3], mfma16(aq[g][0], kf[2], floatx4{}));
        }
        {
            const int jn = (jt + 1 < ntiles) ? j0 + 32 : j0;
            const bf16* kr0 = kb + (long)(jn + l15) * DH;
            const bf16* kr1 = kb + (long)(jn + 16 + l15) * DH;
            kf[0] = ld_frag(kr0 + quad * 8);  kf[1] = ld_frag(kr0 + 32 + quad * 8);
            kf[2] = ld_frag(kr1 + quad * 8);  kf[3] = ld_frag(kr1 + 32 + quad * 8);
        }

        float alpha[2][4];
        #pragma unroll
        for (int g = 0; g < 2; g++) {
            #pragma unroll
            for (int r = 0; r < 4; r++) {
                int qi = qr0 + g * 16 + quad * 4 + r;
                int ja = j0 + l15;
                int jb = j0 + 16 + l15;
                float va  = ((ja < PMEMN) || (ja - PMEMN <= qi)) ? sc[g][0][r] : -1e30f;
                float vb2 = ((jb < PMEMN) || (jb - PMEMN <= qi)) ? sc[g][1][r] : -1e30f;
                float rm = fmaxf(va, vb2);
                #pragma unroll
                for (int off = 1; off < 16; off <<= 1) rm = fmaxf(rm, __shfl_xor(rm, off));
                float mn = fmaxf(mrow[g][r], rm);
                alpha[g][r] = __expf(mrow[g][r] - mn);
                mrow[g][r] = mn;
                float p0 = __expf(va - mn);
                float p1 = __expf(vb2 - mn);
                pb[(g * 16 + quad * 4 + r) * 32 + l15]      = __builtin_bit_cast(short, __float2bfloat16(p0));
                pb[(g * 16 + quad * 4 + r) * 32 + 16 + l15] = __builtin_bit_cast(short, __float2bfloat16(p1));
            }
        }
        __asm__ volatile("" ::: "memory");
        short8 pa0, pa1;
        __builtin_memcpy(&pa0, &pb[l15 * 32 + quad * 8], 16);
        __builtin_memcpy(&pa1, &pb[(16 + l15) * 32 + quad * 8], 16);
        __asm__ volatile("" ::: "memory");
        #pragma unroll
        for (int r = 0; r < 4; r++) { lac[0][r] *= alpha[0][r]; lac[1][r] *= alpha[1][r]; }
        lac[0] = mfma16(pa0, onesB, lac[0]);
        lac[1] = mfma16(pa1, onesB, lac[1]);
        #pragma unroll
        for (int n = 0; n < 4; n++) {
            #pragma unroll
            for (int r = 0; r < 4; r++) { o[0][n][r] *= alpha[0][r]; o[1][n][r] *= alpha[1][r]; }
            o[0][n] = mfma16(pa0, bv[n], o[0][n]);
            o[1][n] = mfma16(pa1, bv[n], o[1][n]);
        }
    }
    #pragma unroll
    for (int g = 0; g < 2; g++) {
        bf16* orow = attn_out + (long)(bw * SEG + qr0 + g * 16 + quad * 4) * DIM + h * DH;
        #pragma unroll
        for (int r = 0; r < 4; r++) {
            float lsum = __shfl(lac[g][r], (lane & 48));
            float inv = 1.0f / lsum;
            #pragma unroll
            for (int n = 0; n < 4; n++)
                orow[(long)r * DIM + n * 16 + l15] = __float2bfloat16(o[g][n][r] * inv);
        }
    }
}

extern "C" void kernel_launch(void* const* d_in, const int* in_sizes, int n_in,
                              void* d_out, int out_size, void* d_ws, size_t ws_size,
                              hipStream_t stream) {
    const float* seq    = (const float*)d_in[0];
    const float* norm_w = (const float*)d_in[1];
    const float* w_qkv  = (const float*)d_in[2];
    const float* w_out  = (const float*)d_in[3];
    const float* pmem   = (const float*)d_in[4];
    // Reference outputs are FLOAT32: d_out = [out, orig_v] fp32.
    float* out   = (float*)d_out;
    float* origv = out + (long)TOK * DIM;

    char* p = (char*)d_ws;
    bf16* xn     = (bf16*)p; p += (long)TOK * DIM * 2;
    bf16* wqkvT  = (bf16*)p; p += (long)NQKV * DIM * 2;
    bf16* woutT  = (bf16*)p; p += (long)DIM * DIM * 2;
    bf16* qbuf   = (bf16*)p; p += (long)TOK * DIM * 2;
    bf16* kpadb  = (bf16*)p; p += (long)NSH * JPAD * DH * 2;
    bf16* vtpadb = (bf16*)p; p += (long)NSH * DH * JPAD * 2;
    bf16* attno  = xn;   // xn dead after QKV GEMM

    rmsnorm_kernel<<<TOK, 256, 0, stream>>>(seq, norm_w, xn);
    transpose_w2<<<dim3(128, 32), dim3(32, 8), 0, stream>>>(w_qkv, w_out, wqkvT, woutT);
    fill_pmem_pad<<<(NSH * PMEMN * DH) / 256, 256, 0, stream>>>(pmem, kpadb, vtpadb);
    gemm_qkv_ep<<<dim3(TOK / 256, NQKV / 256), 512, 0, stream>>>(xn, wqkvT, qbuf, kpadb, vtpadb, origv);
    flash_attn<<<4 * NSH, 256, 0, stream>>>(qbuf, kpadb, vtpadb, attno);
    gemm_bt_f<<<dim3(TOK / 128, DIM / 128), 256, 0, stream>>>(attno, woutT, out, TOK, DIM, DIM);
}

// Round 4
// 247.416 us; speedup vs baseline: 1.0235x; 1.0235x over previous
//
#include <hip/hip_runtime.h>
#include <hip/hip_bf16.h>

#define DIM    1024
#define HEADS  16
#define DH     64
#define SEG    512
#define PMEMN  16
#define TOK    8192        // 2*4096 tokens = 16 segments * 512
#define NQKV   3072
#define JPAD   544         // PMEM + SEG + 16 zero-pad (17 tiles of 32)
#define NSH    256         // 16 segments * 16 heads
#define QK2    264         // 256-col bf16 stage stride (528B, 16B-aligned)
#define VF2    260         // 256-col fp32 stage stride (1040B, 16B-aligned)
#define VT2    257         // 256-col bf16 transpose stride (odd)

typedef __hip_bfloat16 bf16;
typedef __attribute__((ext_vector_type(8))) short short8;   // 8 bf16 = 4 VGPRs
typedef __attribute__((ext_vector_type(4))) float floatx4;  // MFMA C/D frag

__device__ __forceinline__ short8 ld_frag(const bf16* p) {
    return *(const short8*)p;
}
__device__ __forceinline__ floatx4 mfma16(short8 a, short8 b, floatx4 c) {
    return __builtin_amdgcn_mfma_f32_16x16x32_bf16(a, b, c, 0, 0, 0);
}
// async global->LDS DMA, 16 B per lane; LDS dest must be wave base + lane*16
__device__ __forceinline__ void g2lds16(const bf16* g, bf16* l) {
    __builtin_amdgcn_global_load_lds((const __attribute__((address_space(1))) void*)g,
                                     (__attribute__((address_space(3))) void*)l, 16, 0, 0);
}

// ---------------- RMSNorm: fp32 in -> bf16 normalized ----------------
__global__ void rmsnorm_kernel(const float* __restrict__ x, const float* __restrict__ wgt,
                               bf16* __restrict__ xn) {
    int row = blockIdx.x;
    int tid = threadIdx.x;              // 256 threads, 4 floats each
    const float4* xr = (const float4*)(x + (long)row * DIM);
    float4 v = xr[tid];
    float ss = v.x * v.x + v.y * v.y + v.z * v.z + v.w * v.w;
    #pragma unroll
    for (int off = 32; off; off >>= 1) ss += __shfl_xor(ss, off);
    __shared__ float red[4];
    if ((tid & 63) == 0) red[tid >> 6] = ss;
    __syncthreads();
    float tot = red[0] + red[1] + red[2] + red[3];
    float sc = rsqrtf(tot * (1.0f / DIM) + 1.1920929e-07f);
    const float4* wr = (const float4*)wgt;
    float4 w4 = wr[tid];
    bf16* o = xn + (long)row * DIM + tid * 4;
    o[0] = __float2bfloat16(v.x * sc * w4.x);
    o[1] = __float2bfloat16(v.y * sc * w4.y);
    o[2] = __float2bfloat16(v.z * sc * w4.z);
    o[3] = __float2bfloat16(v.w * sc * w4.w);
}

// ---- merged transpose + cast: wqkv [1024][3072] and wout [1024][1024] -> bf16 [C][R] ----
__global__ void transpose_w2(const float* __restrict__ wqkv, const float* __restrict__ wout,
                             bf16* __restrict__ wqkvT, bf16* __restrict__ woutT) {
    __shared__ float tile[32][33];
    int bx = blockIdx.x;
    const float* in; bf16* out; int C, c0;
    if (bx < 96) { in = wqkv; out = wqkvT; C = NQKV; c0 = bx * 32; }
    else         { in = wout; out = woutT; C = DIM;  c0 = (bx - 96) * 32; }
    const int R = DIM;
    int r0 = blockIdx.y * 32;
    int tx = threadIdx.x, ty = threadIdx.y;      // (32,8)
    #pragma unroll
    for (int i = 0; i < 4; i++)
        tile[ty + i * 8][tx] = in[(long)(r0 + ty + i * 8) * C + c0 + tx];
    __syncthreads();
    #pragma unroll
    for (int i = 0; i < 4; i++)
        out[(long)(c0 + ty + i * 8) * R + r0 + tx] = __float2bfloat16(tile[tx][ty + i * 8]);
}

// ------- out-projection GEMM: C[M][N] = A[M][K]*Bt[N][K]^T, fp32 out via LDS stage -------
__global__ __launch_bounds__(256)
void gemm_bt_f(const bf16* __restrict__ A, const bf16* __restrict__ Bt,
               float* __restrict__ C, int M, int N, int K) {
    __shared__ __align__(16) bf16 SMu[128 * 136];    // 34816 B; K-loop uses first 32 KB
    bf16* As = SMu;
    bf16* Bs = SMu + 128 * 64;
    const int tid = threadIdx.x;
    const int wv = tid >> 6;
    const int lane = tid & 63;
    const int quad = lane >> 4, l15 = lane & 15;
    const int wm = (wv >> 1) * 64, wn = (wv & 1) * 64;
    const int bm = blockIdx.x, bn = blockIdx.y;

    const int srow = tid >> 3;
    const int sgch = (tid & 7) ^ (srow & 7);
    const bf16* Ag = A + (long)(bm * 128 + srow) * K + sgch * 8;
    const bf16* Bg = Bt + (long)(bn * 128 + srow) * K + sgch * 8;
    const long row32 = (long)32 * K;

    const int rx0 = ((0 + quad) ^ (l15 & 7)) * 8;
    const int rx1 = ((4 + quad) ^ (l15 & 7)) * 8;

    floatx4 acc[4][4] = {};

    for (int k0 = 0; k0 < K; k0 += 64) {
        __syncthreads();
        #pragma unroll
        for (int i = 0; i < 4; i++) {
            g2lds16(Ag + i * row32 + k0, As + i * 2048 + tid * 8);
            g2lds16(Bg + i * row32 + k0, Bs + i * 2048 + tid * 8);
        }
        __syncthreads();
        #pragma unroll
        for (int kk = 0; kk < 2; kk++) {
            const int rx = kk ? rx1 : rx0;
            short8 af[4], bfr[4];
            #pragma unroll
            for (int i = 0; i < 4; i++) af[i] = ld_frag(&As[(wm + i * 16 + l15) * 64 + rx]);
            #pragma unroll
            for (int j = 0; j < 4; j++) bfr[j] = ld_frag(&Bs[(wn + j * 16 + l15) * 64 + rx]);
            #pragma unroll
            for (int i = 0; i < 4; i++)
                #pragma unroll
                for (int j = 0; j < 4; j++)
                    acc[i][j] = mfma16(af[i], bfr[j], acc[i][j]);
        }
    }
    // ---- fp32 C-write via LDS half-staging: full-line float4 stores ----
    float* SMf = (float*)SMu;            // 64 x 132 fp32
    #pragma unroll
    for (int half = 0; half < 2; half++) {
        __syncthreads();                 // half0: also guards As/Bs reuse
        if ((wv >> 1) == half) {
            #pragma unroll
            for (int i = 0; i < 4; i++)
                #pragma unroll
                for (int j = 0; j < 4; j++)
                    #pragma unroll
                    for (int r = 0; r < 4; r++)
                        SMf[(i * 16 + quad * 4 + r) * 132 + wn + j * 16 + l15] = acc[i][j][r];
        }
        __syncthreads();
        #pragma unroll
        for (int it = 0; it < 8; it++) {
            int cid = it * 256 + tid;
            int rr = cid >> 5, cc = cid & 31;          // 64 rows x 32 float4-chunks
            float4 v4 = *(const float4*)&SMf[rr * 132 + cc * 4];
            *(float4*)&C[(long)(bm * 128 + half * 64 + rr) * N + bn * 128 + cc * 4] = v4;
        }
    }
}

// ======= QKV GEMM, 128x256 tile, 8 waves, 2-phase/K-tile counted-vmcnt schedule =======
// Grid 64x12 = 768 blocks = exactly 3 blocks/CU: zero dispatch-round tail (the R3
// 256x256 version was 384 blocks = 1.5 rounds -> 75% util).
// Phase nh computes C[:, nh*128 .. +128); wave (qrow,qcol) owns a 32x64 piece.
// A-frags are shared by both phases (loaded once in P1, reused in P2).
// All 6 next-tile loads (A 2, B0 2, B1 2) issue in P1 -> each consumed half-tile
// was issued 2 phases earlier. Waits: end-P1 vmcnt(6) (drains B1 of current),
// end-P2 vmcnt(2) (drains A,B0 of next). Never 0 in the main loop.
__global__ __launch_bounds__(512, 2)
void gemm_qkv_ep(const bf16* __restrict__ A, const bf16* __restrict__ Bt,
                 bf16* __restrict__ qbuf, bf16* __restrict__ kpad,
                 bf16* __restrict__ vtpad, float* __restrict__ origv) {
    __shared__ __align__(16) bf16 SMEM[49152];   // 96 KiB: As[2][8192] | Bs[2][16384]
    const int tid = threadIdx.x;
    const int wv = tid >> 6;                      // 0..7
    const int lane = tid & 63;
    const int quad = lane >> 4, l15 = lane & 15;
    const int qrow = wv >> 1;                     // 0..3 (32-row band)
    const int qcol = wv & 1;                      // 0..1 (64-col band in 128-half)
    const int bm = blockIdx.x, bn = blockIdx.y;

    const int rowt = tid >> 3;                    // 0..63
    const int sgch = (tid & 7) ^ (rowt & 7);      // source chunk pre-swizzle
    const bf16* Asrc = A  + (long)(bm * 128 + rowt) * DIM + sgch * 8;
    const bf16* Bsrc = Bt + (long)(bn * 256 + rowt) * DIM + sgch * 8;

    // each g2lds16 sweep: 512 threads x 16B = 8 KB = 64 rows x 64 cols
#define STG_A(buf, kt) do { \
        g2lds16(Asrc + (long)(kt) * 64,            SMEM + (buf) * 8192 + tid * 8); \
        g2lds16(Asrc + (long)64 * DIM + (kt) * 64, SMEM + (buf) * 8192 + 4096 + tid * 8); \
    } while (0)
#define STG_B0(buf, kt) do { \
        g2lds16(Bsrc + (long)(kt) * 64,            SMEM + 16384 + (buf) * 16384 + tid * 8); \
        g2lds16(Bsrc + (long)64 * DIM + (kt) * 64, SMEM + 16384 + (buf) * 16384 + 4096 + tid * 8); \
    } while (0)
#define STG_B1(buf, kt) do { \
        g2lds16(Bsrc + (long)128 * DIM + (kt) * 64, SMEM + 16384 + (buf) * 16384 + 8192 + tid * 8); \
        g2lds16(Bsrc + (long)192 * DIM + (kt) * 64, SMEM + 16384 + (buf) * 16384 + 12288 + tid * 8); \
    } while (0)

    floatx4 acc[2][2][4] = {};   // [nh][m][n]

#define PHASE1(CUR, NXT, KTN) do { \
        _Pragma("unroll") \
        for (int m = 0; m < 2; m++) \
            _Pragma("unroll") \
            for (int kk = 0; kk < 2; kk++) \
                af[kk][m] = ld_frag(&SMEM[(CUR) * 8192 + (qrow * 32 + m * 16 + l15) * 64 + ((kk * 4 + quad) ^ (l15 & 7)) * 8]); \
        short8 bf0[2][4]; \
        _Pragma("unroll") \
        for (int n = 0; n < 4; n++) \
            _Pragma("unroll") \
            for (int kk = 0; kk < 2; kk++) \
                bf0[kk][n] = ld_frag(&SMEM[16384 + (CUR) * 16384 + (qcol * 64 + n * 16 + l15) * 64 + ((kk * 4 + quad) ^ (l15 & 7)) * 8]); \
        STG_A(NXT, KTN); STG_B0(NXT, KTN); STG_B1(NXT, KTN); \
        __builtin_amdgcn_s_barrier(); \
        asm volatile("s_waitcnt lgkmcnt(0)" ::: "memory"); \
        __builtin_amdgcn_sched_barrier(0); \
        __builtin_amdgcn_s_setprio(1); \
        _Pragma("unroll") \
        for (int m = 0; m < 2; m++) \
            _Pragma("unroll") \
            for (int n = 0; n < 4; n++) { \
                acc[0][m][n] = mfma16(af[0][m], bf0[0][n], acc[0][m][n]); \
                acc[0][m][n] = mfma16(af[1][m], bf0[1][n], acc[0][m][n]); \
            } \
        __builtin_amdgcn_s_setprio(0); \
        asm volatile("s_waitcnt vmcnt(6)" ::: "memory"); \
        __builtin_amdgcn_s_barrier(); \
    } while (0)

#define PHASE2(CUR) do { \
        short8 bf1[2][4]; \
        _Pragma("unroll") \
        for (int n = 0; n < 4; n++) \
            _Pragma("unroll") \
            for (int kk = 0; kk < 2; kk++) \
                bf1[kk][n] = ld_frag(&SMEM[16384 + (CUR) * 16384 + (128 + qcol * 64 + n * 16 + l15) * 64 + ((kk * 4 + quad) ^ (l15 & 7)) * 8]); \
        __builtin_amdgcn_s_barrier(); \
        asm volatile("s_waitcnt lgkmcnt(0)" ::: "memory"); \
        __builtin_amdgcn_sched_barrier(0); \
        __builtin_amdgcn_s_setprio(1); \
        _Pragma("unroll") \
        for (int m = 0; m < 2; m++) \
            _Pragma("unroll") \
            for (int n = 0; n < 4; n++) { \
                acc[1][m][n] = mfma16(af[0][m], bf1[0][n], acc[1][m][n]); \
                acc[1][m][n] = mfma16(af[1][m], bf1[1][n], acc[1][m][n]); \
            } \
        __builtin_amdgcn_s_setprio(0); \
        asm volatile("s_waitcnt vmcnt(2)" ::: "memory"); \
        __builtin_amdgcn_s_barrier(); \
    } while (0)

    // prologue: K-tile 0 into buf0 (A, B0, B1); wait A+B0 landed (B1 outstanding)
    STG_A(0, 0); STG_B0(0, 0); STG_B1(0, 0);
    asm volatile("s_waitcnt vmcnt(2)" ::: "memory");
    __builtin_amdgcn_s_barrier();

    for (int kt2 = 0; kt2 < 16; kt2 += 2) {
        const int kn1 = kt2 + 1;
        const int kn2 = (kt2 + 2 < 16) ? (kt2 + 2) : 15;   // last: dummy re-stage
        {
            short8 af[2][2];
            PHASE1(0, 1, kn1);
            PHASE2(0);
        }
        {
            short8 af[2][2];
            PHASE1(1, 0, kn2);
            PHASE2(1);
        }
    }
    asm volatile("s_waitcnt vmcnt(0)" ::: "memory");   // drain dummies before LDS reuse
    __builtin_amdgcn_s_barrier();
#undef PHASE1
#undef PHASE2
#undef STG_A
#undef STG_B0
#undef STG_B1

    const int tok0 = bm * 128;
    const int seg = tok0 >> 9;          // block fully inside one segment
    const int s0 = tok0 & 511;

    if (bn < 8) {
        // ---- q (bn<4) or k block: rope in-register, stage bf16, vector stores ----
        const bool isq = (bn < 4);
        const int cb = (bn & 3) * 256;                 // dcol base within q or k
        #pragma unroll
        for (int nh = 0; nh < 2; nh++)
            #pragma unroll
            for (int n = 0; n < 4; n++) {
                int col = nh * 128 + qcol * 64 + n * 16 + l15;
                int dcol = cb + col;
                int dh = dcol & 63;
                int pr = dh >> 1;
                float invf = __expf(-(float)pr * (9.210340371976184f / 32.0f));
                const bool odd = dh & 1;
                #pragma unroll
                for (int m = 0; m < 2; m++)
                    #pragma unroll
                    for (int r = 0; r < 4; r++) {
                        int lrow = qrow * 32 + m * 16 + quad * 4 + r;   // 0..127
                        int sl = s0 + lrow;
                        float sn, cs;
                        __sincosf((float)sl * invf, &sn, &cs);
                        float v = acc[nh][m][n][r];
                        float px = __shfl_xor(v, 1);
                        float y = odd ? (v * cs + px * sn) : (v * cs - px * sn);
                        if (isq) y *= 0.125f;          // fold DH^-0.5 (exact)
                        SMEM[lrow * QK2 + col] = __float2bfloat16(y);
                    }
            }
        __syncthreads();
        #pragma unroll
        for (int it = 0; it < 8; it++) {
            int cid = it * 512 + tid;
            int rr = cid >> 5, cc = cid & 31;          // 128 rows x 32 short8-chunks
            short8 pk = *(const short8*)&SMEM[rr * QK2 + cc * 8];
            if (isq) {
                *(short8*)&qbuf[(long)(tok0 + rr) * DIM + cb + cc * 8] = pk;
            } else {
                int dcol = cb + cc * 8;
                int h = dcol >> 6, dh = dcol & 63;
                *(short8*)&kpad[(((long)(seg * 16 + h) * JPAD) + PMEMN + s0 + rr) * DH + dh] = pk;
            }
        }
    } else {
        // ---- v block: origv fp32 via LDS half-staging + bf16 transpose -> vtpad ----
        const int vb = (bn - 8) * 256;
        float* SMf = (float*)SMEM;                     // 64 x VF2 fp32
        #pragma unroll
        for (int half = 0; half < 2; half++) {
            if (half) __syncthreads();                 // prior store reads done
            if ((qrow >> 1) == half) {                 // waves owning rows half*64..+63
                #pragma unroll
                for (int nh = 0; nh < 2; nh++)
                    #pragma unroll
                    for (int m = 0; m < 2; m++)
                        #pragma unroll
                        for (int n = 0; n < 4; n++)
                            #pragma unroll
                            for (int r = 0; r < 4; r++)
                                SMf[((qrow & 1) * 32 + m * 16 + quad * 4 + r) * VF2 + nh * 128 + qcol * 64 + n * 16 + l15] =
                                    acc[nh][m][n][r];
            }
            __syncthreads();
            #pragma unroll
            for (int it = 0; it < 8; it++) {
                int cid = it * 512 + tid;
                int rr = cid >> 6, cc = cid & 63;      // 64 rows x 64 float4-chunks
                float4 v4 = *(const float4*)&SMf[rr * VF2 + cc * 4];
                int sl = s0 + half * 64 + rr;
                int vcol = vb + cc * 4;
                int h = vcol >> 6, dh = vcol & 63;
                *(float4*)&origv[((long)(seg * 16 + h) * SEG + sl) * DH + dh] = v4;
            }
        }
        __syncthreads();
        #pragma unroll
        for (int nh = 0; nh < 2; nh++)
            #pragma unroll
            for (int m = 0; m < 2; m++)
                #pragma unroll
                for (int n = 0; n < 4; n++)
                    #pragma unroll
                    for (int r = 0; r < 4; r++)
                        SMEM[(qrow * 32 + m * 16 + quad * 4 + r) * VT2 + nh * 128 + qcol * 64 + n * 16 + l15] =
                            __float2bfloat16(acc[nh][m][n][r]);
        __syncthreads();
        #pragma unroll
        for (int it = 0; it < 8; it++) {
            int cid = it * 512 + tid;
            int orow = cid >> 4;                       // local v-col 0..255
            int tch = cid & 15;                        // token chunk of 8
            int vcol = vb + orow;
            int h = vcol >> 6, dh = vcol & 63;
            short8 pk;
            #pragma unroll
            for (int k = 0; k < 8; k++)
                pk[k] = __builtin_bit_cast(short, SMEM[(tch * 8 + k) * VT2 + orow]);
            *(short8*)&vtpad[(((long)(seg * 16 + h) * DH + dh) * JPAD) + PMEMN + s0 + tch * 8] = pk;
        }
    }
}

// ------------- pmem rows into kpad/vtpad + zero tail pad -------------
__global__ void fill_pmem_pad(const float* __restrict__ pmem, bf16* __restrict__ kpad,
                              bf16* __restrict__ vtpad) {
    int gid = blockIdx.x * 256 + threadIdx.x;
    int dh = gid & 63, j = (gid >> 6) & 15, sh = gid >> 10;
    int h = sh & 15;
    float kv = pmem[((0 * HEADS + h) * PMEMN + j) * DH + dh];
    float vv = pmem[((1 * HEADS + h) * PMEMN + j) * DH + dh];
    kpad[((long)sh * JPAD + j) * DH + dh] = __float2bfloat16(kv);
    vtpad[((long)sh * DH + dh) * JPAD + j] = __float2bfloat16(vv);
    kpad[((long)sh * JPAD + PMEMN + SEG + j) * DH + dh] = __float2bfloat16(0.0f);
    vtpad[((long)sh * DH + dh) * JPAD + PMEMN + SEG + j] = __float2bfloat16(0.0f);
}

// ------- flash attention v3: 1 wave = 32 q rows, NO block barriers in K-loop -------
__global__ __launch_bounds__(256, 3)
void flash_attn(const bf16* __restrict__ qbuf, const bf16* __restrict__ kpad,
                const bf16* __restrict__ vtpad, bf16* __restrict__ attn_out) {
    const int bid = blockIdx.x;
    const int sh = bid & (NSH - 1);
    const int qblk = bid >> 8;
    const int wv = threadIdx.x >> 6;
    const int lane = threadIdx.x & 63;
    const int quad = lane >> 4, l15 = lane & 15;
    const int qr0 = qblk * 128 + wv * 32;
    const int bw = sh >> 4, h = sh & 15;

    __shared__ __align__(16) short pbuf[4][32 * 32];   // per-wave P tile
    short* pb = pbuf[wv];

    const bf16* qr_g0 = qbuf + (long)(bw * SEG + qr0 + l15) * DIM + h * DH;
    const bf16* qr_g1 = qbuf + (long)(bw * SEG + qr0 + 16 + l15) * DIM + h * DH;
    short8 aq[2][2] = {{ld_frag(qr_g0 + quad * 8), ld_frag(qr_g0 + 32 + quad * 8)},
                       {ld_frag(qr_g1 + quad * 8), ld_frag(qr_g1 + 32 + quad * 8)}};

    // ones B-fragment: B[k][0]=1 -> D[:,0] = row-sum of P
    const short bf16one = (short)0x3F80;
    short8 onesB;
    #pragma unroll
    for (int i = 0; i < 8; i++) onesB[i] = (l15 == 0) ? bf16one : (short)0;

    float mrow[2][4];
    floatx4 o[2][4] = {};
    floatx4 lac[2] = {};
    #pragma unroll
    for (int g = 0; g < 2; g++)
        #pragma unroll
        for (int r = 0; r < 4; r++) mrow[g][r] = -1e30f;

    const bf16* kb = kpad + (long)sh * JPAD * DH;
    const bf16* vbp = vtpad + (long)sh * DH * JPAD;

    const int ntiles = (qr0 + 47) / 32 + 1;

    short8 kf[4];
    {
        const bf16* kr0 = kb + (long)l15 * DH;
        const bf16* kr1 = kb + (long)(16 + l15) * DH;
        kf[0] = ld_frag(kr0 + quad * 8);  kf[1] = ld_frag(kr0 + 32 + quad * 8);
        kf[2] = ld_frag(kr1 + quad * 8);  kf[3] = ld_frag(kr1 + 32 + quad * 8);
    }

    for (int jt = 0; jt < ntiles; ++jt) {
        const int j0 = jt * 32;
        short8 bv[4];
        #pragma unroll
        for (int n = 0; n < 4; n++)
            bv[n] = ld_frag(vbp + (long)(n * 16 + l15) * JPAD + j0 + quad * 8);

        floatx4 sc[2][2];
        #pragma unroll
        for (int g = 0; g < 2; g++) {
            sc[g][0] = mfma16(aq[g][1], kf[1], mfma16(aq[g][0], kf[0], floatx4{}));
            sc[g][1] = mfma16(aq[g][1], kf[3], mfma16(aq[g][0], kf[2], floatx4{}));
        }
        {
            const int jn = (jt + 1 < ntiles) ? j0 + 32 : j0;
            const bf16* kr0 = kb + (long)(jn + l15) * DH;
            const bf16* kr1 = kb + (long)(jn + 16 + l15) * DH;
            kf[0] = ld_frag(kr0 + quad * 8);  kf[1] = ld_frag(kr0 + 32 + quad * 8);
            kf[2] = ld_frag(kr1 + quad * 8);  kf[3] = ld_frag(kr1 + 32 + quad * 8);
        }

        float alpha[2][4];
        #pragma unroll
        for (int g = 0; g < 2; g++) {
            #pragma unroll
            for (int r = 0; r < 4; r++) {
                int qi = qr0 + g * 16 + quad * 4 + r;
                int ja = j0 + l15;
                int jb = j0 + 16 + l15;
                float va  = ((ja < PMEMN) || (ja - PMEMN <= qi)) ? sc[g][0][r] : -1e30f;
                float vb2 = ((jb < PMEMN) || (jb - PMEMN <= qi)) ? sc[g][1][r] : -1e30f;
                float rm = fmaxf(va, vb2);
                #pragma unroll
                for (int off = 1; off < 16; off <<= 1) rm = fmaxf(rm, __shfl_xor(rm, off));
                float mn = fmaxf(mrow[g][r], rm);
                alpha[g][r] = __expf(mrow[g][r] - mn);
                mrow[g][r] = mn;
                float p0 = __expf(va - mn);
                float p1 = __expf(vb2 - mn);
                pb[(g * 16 + quad * 4 + r) * 32 + l15]      = __builtin_bit_cast(short, __float2bfloat16(p0));
                pb[(g * 16 + quad * 4 + r) * 32 + 16 + l15] = __builtin_bit_cast(short, __float2bfloat16(p1));
            }
        }
        __asm__ volatile("" ::: "memory");
        short8 pa0, pa1;
        __builtin_memcpy(&pa0, &pb[l15 * 32 + quad * 8], 16);
        __builtin_memcpy(&pa1, &pb[(16 + l15) * 32 + quad * 8], 16);
        __asm__ volatile("" ::: "memory");
        #pragma unroll
        for (int r = 0; r < 4; r++) { lac[0][r] *= alpha[0][r]; lac[1][r] *= alpha[1][r]; }
        lac[0] = mfma16(pa0, onesB, lac[0]);
        lac[1] = mfma16(pa1, onesB, lac[1]);
        #pragma unroll
        for (int n = 0; n < 4; n++) {
            #pragma unroll
            for (int r = 0; r < 4; r++) { o[0][n][r] *= alpha[0][r]; o[1][n][r] *= alpha[1][r]; }
            o[0][n] = mfma16(pa0, bv[n], o[0][n]);
            o[1][n] = mfma16(pa1, bv[n], o[1][n]);
        }
    }
    #pragma unroll
    for (int g = 0; g < 2; g++) {
        bf16* orow = attn_out + (long)(bw * SEG + qr0 + g * 16 + quad * 4) * DIM + h * DH;
        #pragma unroll
        for (int r = 0; r < 4; r++) {
            float lsum = __shfl(lac[g][r], (lane & 48));
            float inv = 1.0f / lsum;
            #pragma unroll
            for (int n = 0; n < 4; n++)
                orow[(long)r * DIM + n * 16 + l15] = __float2bfloat16(o[g][n][r] * inv);
        }
    }
}

extern "C" void kernel_launch(void* const* d_in, const int* in_sizes, int n_in,
                              void* d_out, int out_size, void* d_ws, size_t ws_size,
                              hipStream_t stream) {
    const float* seq    = (const float*)d_in[0];
    const float* norm_w = (const float*)d_in[1];
    const float* w_qkv  = (const float*)d_in[2];
    const float* w_out  = (const float*)d_in[3];
    const float* pmem   = (const float*)d_in[4];
    // Reference outputs are FLOAT32: d_out = [out, orig_v] fp32.
    float* out   = (float*)d_out;
    float* origv = out + (long)TOK * DIM;

    char* p = (char*)d_ws;
    bf16* xn     = (bf16*)p; p += (long)TOK * DIM * 2;
    bf16* wqkvT  = (bf16*)p; p += (long)NQKV * DIM * 2;
    bf16* woutT  = (bf16*)p; p += (long)DIM * DIM * 2;
    bf16* qbuf   = (bf16*)p; p += (long)TOK * DIM * 2;
    bf16* kpadb  = (bf16*)p; p += (long)NSH * JPAD * DH * 2;
    bf16* vtpadb = (bf16*)p; p += (long)NSH * DH * JPAD * 2;
    bf16* attno  = xn;   // xn dead after QKV GEMM

    rmsnorm_kernel<<<TOK, 256, 0, stream>>>(seq, norm_w, xn);
    transpose_w2<<<dim3(128, 32), dim3(32, 8), 0, stream>>>(w_qkv, w_out, wqkvT, woutT);
    fill_pmem_pad<<<(NSH * PMEMN * DH) / 256, 256, 0, stream>>>(pmem, kpadb, vtpadb);
    gemm_qkv_ep<<<dim3(TOK / 128, NQKV / 256), 512, 0, stream>>>(xn, wqkvT, qbuf, kpadb, vtpadb, origv);
    flash_attn<<<4 * NSH, 256, 0, stream>>>(qbuf, kpadb, vtpadb, attno);
    gemm_bt_f<<<dim3(TOK / 128, DIM / 128), 256, 0, stream>>>(attno, woutT, out, TOK, DIM, DIM);
}